// Round 2
// baseline (203.446 us; speedup 1.0000x reference)
//
#include <hip/hip_runtime.h>

#define N_Q   50000
#define N_S   50000
#define M_NB  32
#define K_PTS 15
#define CIN   64
#define COUT  64
#define NPAIRS (N_Q * M_NB)

// ws layout: [0,16): event counter (int) | [16, 16+N_S*16): float4 s4[N_S]
//            [S4_END, ...): int4 events[]
#define S4_OFF   16
#define S4_BYTES (N_S * 16)
#define EV_OFF   (S4_OFF + S4_BYTES)   // 800016 -> pad to 800032 below

// ---------- kernel A: support [N0,3] -> float4 [N0,4] ----------
__global__ __launch_bounds__(256) void transpose_support(
    const float* __restrict__ support, float4* __restrict__ s4)
{
    int i = blockIdx.x * 256 + threadIdx.x;
    if (i < N_S) {
        s4[i] = make_float4(support[i * 3 + 0], support[i * 3 + 1],
                            support[i * 3 + 2], 0.f);
    }
}

// ---------- kernel B: one thread per (n,m) pair; emit sparse events ----------
// w[k][m] > 0 requires ||nb - kp|| < 0.05 with ||kp|| <= 0.0495
//   => ||nb||^2 < 0.009901  (use 0.0101 conservative)
template <int USE_S4>
__global__ __launch_bounds__(256) void pair_kernel(
    const float*  __restrict__ query,     // [N,3]
    const float*  __restrict__ support,   // [N0,3] (fallback path)
    const float4* __restrict__ s4,        // [N0]   (fast path)
    const int*    __restrict__ neighbors, // [N,M] flat
    const float*  __restrict__ kpts,      // [K,3]
    int*          __restrict__ counter,
    int4*         __restrict__ events,
    int cap)
{
    __shared__ float s_kx[K_PTS], s_ky[K_PTS], s_kz[K_PTS], s_kk[K_PTS];
    if (threadIdx.x < K_PTS) {
        float kx = kpts[threadIdx.x * 3 + 0];
        float ky = kpts[threadIdx.x * 3 + 1];
        float kz = kpts[threadIdx.x * 3 + 2];
        s_kx[threadIdx.x] = kx; s_ky[threadIdx.x] = ky; s_kz[threadIdx.x] = kz;
        s_kk[threadIdx.x] = kx * kx + ky * ky + kz * kz;
    }
    __syncthreads();

    const int t = blockIdx.x * 256 + threadIdx.x;   // grid sized exactly NPAIRS
    const int n = t >> 5;                           // query index
    const int idx = neighbors[t];                   // coalesced
    if (idx >= N_S) return;                         // shadow neighbor: w == 0

    float sx, sy, sz;
    if (USE_S4) {
        float4 s = s4[idx];                         // one dwordx4 gather
        sx = s.x; sy = s.y; sz = s.z;
    } else {
        sx = support[idx * 3 + 0];
        sy = support[idx * 3 + 1];
        sz = support[idx * 3 + 2];
    }
    const float dx = sx - query[n * 3 + 0];         // query: L1-broadcast
    const float dy = sy - query[n * 3 + 1];
    const float dz = sz - query[n * 3 + 2];
    const float nn = dx * dx + dy * dy + dz * dz;
    if (nn >= 0.0101f) return;

    #pragma unroll
    for (int k = 0; k < K_PTS; ++k) {
        float dot = dx * s_kx[k] + dy * s_ky[k] + dz * s_kz[k];
        float sq  = nn - 2.f * dot + s_kk[k];       // same expansion as reference
        sq = fmaxf(sq, 0.f);
        if (sq < 0.0025f) {                          // sqrt(sq) < 0.05 => w > 0
            float w = 1.f - sqrtf(sq) * 20.f;        // 1/0.05 == 20 exactly
            int slot = atomicAdd(counter, 1);
            if (slot < cap)
                events[slot] = make_int4(n, k, idx, __float_as_int(w));
        }
    }
}

// ---------- kernel C: one wave per event, 64x64 GEMV, atomic scatter ----------
__global__ __launch_bounds__(256) void gemv_kernel(
    const int*  __restrict__ counter,
    const int4* __restrict__ events,
    int cap,
    const float* __restrict__ x,       // [N0,CIN]
    const float* __restrict__ weight,  // [K,CIN,COUT]
    float*       __restrict__ out)     // [N,COUT]
{
    const int lane   = threadIdx.x & 63;
    const int wv     = (blockIdx.x * blockDim.x + threadIdx.x) >> 6;
    const int nwaves = (gridDim.x * blockDim.x) >> 6;
    const int cnt    = min(counter[0], cap);

    for (int e = wv; e < cnt; e += nwaves) {
        const int4 ev = events[e];                  // n, k, idx, w
        const float w = __int_as_float(ev.w);
        const float fv = x[ev.z * CIN + lane];      // coalesced 256B row
        const float* wp = weight + ev.y * CIN * COUT + lane;  // L2-hot 16KB row
        float t = 0.f;
        #pragma unroll
        for (int c = 0; c < CIN; ++c)
            t = fmaf(__shfl(fv, c), wp[c * COUT], t);
        atomicAdd(&out[ev.x * COUT + lane], w * t);
    }
}

extern "C" void kernel_launch(void* const* d_in, const int* in_sizes, int n_in,
                              void* d_out, int out_size, void* d_ws, size_t ws_size,
                              hipStream_t stream) {
    const float* query     = (const float*)d_in[0];
    const float* support   = (const float*)d_in[1];
    const int*   neighbors = (const int*)  d_in[2];
    const float* x         = (const float*)d_in[3];
    const float* kpts      = (const float*)d_in[4];
    const float* weight    = (const float*)d_in[5];
    float*       out       = (float*)d_out;

    char* ws = (char*)d_ws;
    int*    counter = (int*)ws;
    float4* s4      = (float4*)(ws + S4_OFF);
    const size_t ev_off = (EV_OFF + 31) & ~size_t(31);

    const bool use_s4 = ws_size >= ev_off + (1u << 20);  // s4 + >=1MB of events
    int4* events;
    int   cap;
    if (use_s4) {
        events = (int4*)(ws + ev_off);
        cap    = (int)((ws_size - ev_off) / sizeof(int4));
    } else {
        events = (int4*)(ws + 16);
        cap    = (int)((ws_size - 16) / sizeof(int4));
    }

    hipMemsetAsync(d_out, 0, (size_t)N_Q * COUT * sizeof(float), stream);
    hipMemsetAsync(d_ws, 0, 16, stream);

    if (use_s4) {
        transpose_support<<<(N_S + 255) / 256, 256, 0, stream>>>(support, s4);
        pair_kernel<1><<<NPAIRS / 256, 256, 0, stream>>>(
            query, support, s4, neighbors, kpts, counter, events, cap);
    } else {
        pair_kernel<0><<<NPAIRS / 256, 256, 0, stream>>>(
            query, support, s4, neighbors, kpts, counter, events, cap);
    }
    gemv_kernel<<<256, 256, 0, stream>>>(counter, events, cap, x, weight, out);
}

// Round 3
// 74.439 us; speedup vs baseline: 2.7331x; 2.7331x over previous
//
#include <hip/hip_runtime.h>

#define N_Q   50000
#define N_S   50000
#define M_NB  32
#define K_PTS 15
#define CIN   64
#define COUT  64
#define NPAIRS (N_Q * M_NB)
#define NBUCK 256

// ws layout:
//   [0, 1024)                 : int counters[NBUCK]
//   [1024, 1024 + N_S*16)     : float4 s4[N_S]          (fast path only)
//   [EV_OFF, ...)             : int4 events[NBUCK][cap]
#define CTR_BYTES 1024
#define S4_BYTES  (N_S * 16)
#define EV_OFF    (CTR_BYTES + S4_BYTES)   // 801024, 16B aligned

// ---------- kernel A: support [N0,3] -> float4 [N0,4]; also zero counters ----------
__global__ __launch_bounds__(256) void transpose_support(
    const float* __restrict__ support, float4* __restrict__ s4,
    int* __restrict__ counters)
{
    int i = blockIdx.x * 256 + threadIdx.x;
    if (blockIdx.x == 0) counters[threadIdx.x] = 0;
    if (i < N_S) {
        s4[i] = make_float4(support[i * 3 + 0], support[i * 3 + 1],
                            support[i * 3 + 2], 0.f);
    }
}

__global__ __launch_bounds__(256) void zero_counters(int* __restrict__ counters)
{
    counters[threadIdx.x] = 0;
}

// ---------- kernel B: one thread per (n,m) pair; emit events into buckets ----------
// w[k][m] > 0 requires ||nb - kp|| < 0.05 with ||kp|| <= 0.0495
//   => ||nb||^2 < 0.009901  (use 0.0101 conservative)
template <int USE_S4>
__global__ __launch_bounds__(256) void pair_kernel(
    const float*  __restrict__ query,     // [N,3]
    const float*  __restrict__ support,   // [N0,3] (fallback path)
    const float4* __restrict__ s4,        // [N0]   (fast path)
    const int*    __restrict__ neighbors, // [N,M] flat
    const float*  __restrict__ kpts,      // [K,3]
    int*          __restrict__ counters,  // [NBUCK]
    int4*         __restrict__ events,    // [NBUCK][cap]
    int cap)
{
    __shared__ float s_kx[K_PTS], s_ky[K_PTS], s_kz[K_PTS], s_kk[K_PTS];
    if (threadIdx.x < K_PTS) {
        float kx = kpts[threadIdx.x * 3 + 0];
        float ky = kpts[threadIdx.x * 3 + 1];
        float kz = kpts[threadIdx.x * 3 + 2];
        s_kx[threadIdx.x] = kx; s_ky[threadIdx.x] = ky; s_kz[threadIdx.x] = kz;
        s_kk[threadIdx.x] = kx * kx + ky * ky + kz * kz;
    }
    __syncthreads();

    const int t = blockIdx.x * 256 + threadIdx.x;   // grid == NPAIRS threads
    const int n = t >> 5;
    const int idx = neighbors[t];                   // coalesced
    if (idx >= N_S) return;                         // shadow neighbor: w == 0

    float sx, sy, sz;
    if (USE_S4) {
        float4 s = s4[idx];                         // one dwordx4 gather
        sx = s.x; sy = s.y; sz = s.z;
    } else {
        sx = support[idx * 3 + 0];
        sy = support[idx * 3 + 1];
        sz = support[idx * 3 + 2];
    }
    const float dx = sx - query[n * 3 + 0];
    const float dy = sy - query[n * 3 + 1];
    const float dz = sz - query[n * 3 + 2];
    const float nn = dx * dx + dy * dy + dz * dz;
    if (nn >= 0.0101f) return;

    const int bucket = blockIdx.x & (NBUCK - 1);
    int* ctr  = counters + bucket;
    int4* evb = events + (size_t)bucket * cap;

    #pragma unroll
    for (int k = 0; k < K_PTS; ++k) {
        float dot = dx * s_kx[k] + dy * s_ky[k] + dz * s_kz[k];
        float sq  = nn - 2.f * dot + s_kk[k];       // same expansion as reference
        sq = fmaxf(sq, 0.f);
        if (sq < 0.0025f) {                          // sqrt(sq) < 0.05 => w > 0
            float w = 1.f - sqrtf(sq) * 20.f;        // 1/0.05 == 20 exactly
            int slot = atomicAdd(ctr, 1);
            if (slot < cap)
                evb[slot] = make_int4(n, k, idx, __float_as_int(w));
        }
    }
}

// ---------- kernel C: block b owns bucket b; waves do 64x64 GEMV per event ----------
__global__ __launch_bounds__(256) void gemv_kernel(
    const int*  __restrict__ counters,
    const int4* __restrict__ events,
    int cap,
    const float* __restrict__ x,       // [N0,CIN]
    const float* __restrict__ weight,  // [K,CIN,COUT]
    float*       __restrict__ out)     // [N,COUT]
{
    const int lane = threadIdx.x & 63;
    const int wv   = threadIdx.x >> 6;              // 0..3
    const int b    = blockIdx.x;                    // bucket
    const int cnt  = min(counters[b], cap);
    const int4* evb = events + (size_t)b * cap;

    for (int e = wv; e < cnt; e += 4) {
        const int4 ev = evb[e];                     // n, k, idx, w
        const float w = __int_as_float(ev.w);
        const float fv = x[ev.z * CIN + lane];      // coalesced 256B row
        const float* wp = weight + ev.y * CIN * COUT + lane;  // L2-hot row
        float t = 0.f;
        #pragma unroll
        for (int c = 0; c < CIN; ++c)
            t = fmaf(__shfl(fv, c), wp[c * COUT], t);
        atomicAdd(&out[ev.x * COUT + lane], w * t);
    }
}

extern "C" void kernel_launch(void* const* d_in, const int* in_sizes, int n_in,
                              void* d_out, int out_size, void* d_ws, size_t ws_size,
                              hipStream_t stream) {
    const float* query     = (const float*)d_in[0];
    const float* support   = (const float*)d_in[1];
    const int*   neighbors = (const int*)  d_in[2];
    const float* x         = (const float*)d_in[3];
    const float* kpts      = (const float*)d_in[4];
    const float* weight    = (const float*)d_in[5];
    float*       out       = (float*)d_out;

    char*   ws       = (char*)d_ws;
    int*    counters = (int*)ws;
    float4* s4       = (float4*)(ws + CTR_BYTES);

    const bool use_s4 = ws_size >= (size_t)EV_OFF + (2u << 20);
    int4* events;
    int   cap;
    if (use_s4) {
        events = (int4*)(ws + EV_OFF);
        cap    = (int)((ws_size - EV_OFF) / sizeof(int4) / NBUCK);
    } else {
        events = (int4*)(ws + CTR_BYTES);
        cap    = (int)((ws_size - CTR_BYTES) / sizeof(int4) / NBUCK);
    }

    hipMemsetAsync(d_out, 0, (size_t)N_Q * COUT * sizeof(float), stream);

    if (use_s4) {
        transpose_support<<<(N_S + 255) / 256, 256, 0, stream>>>(support, s4, counters);
        pair_kernel<1><<<NPAIRS / 256, 256, 0, stream>>>(
            query, support, s4, neighbors, kpts, counters, events, cap);
    } else {
        zero_counters<<<1, 256, 0, stream>>>(counters);
        pair_kernel<0><<<NPAIRS / 256, 256, 0, stream>>>(
            query, support, s4, neighbors, kpts, counters, events, cap);
    }
    gemv_kernel<<<NBUCK, 256, 0, stream>>>(counters, events, cap, x, weight, out);
}

// Round 4
// 46.834 us; speedup vs baseline: 4.3440x; 1.5894x over previous
//
#include <hip/hip_runtime.h>

#define N_Q   50000
#define N_S   50000
#define M_NB  32
#define K_PTS 15
#define CIN   64
#define COUT  64
#define NPAIRS (N_Q * M_NB)
#define NBUCK 256
#define GEMV_BLOCKS_PER_BUCKET 8

// ws layout:
//   [0, 1024)             : int counters[NBUCK]
//   [1024, 1024 + N_S*16) : float4 s4[N_S]
//   [EV_OFF, ...)         : int4 events[NBUCK][cap]
#define CTR_BYTES 1024
#define S4_BYTES  (N_S * 16)
#define EV_OFF    (CTR_BYTES + S4_BYTES)

// ---------- kernel A: support [N0,3] -> float4 [N0,4]; also zero counters ----------
__global__ __launch_bounds__(256) void transpose_support(
    const float* __restrict__ support, float4* __restrict__ s4,
    int* __restrict__ counters)
{
    int i = blockIdx.x * 256 + threadIdx.x;
    if (blockIdx.x == 0) counters[threadIdx.x] = 0;
    if (i < N_S) {
        s4[i] = make_float4(support[i * 3 + 0], support[i * 3 + 1],
                            support[i * 3 + 2], 0.f);
    }
}

__global__ __launch_bounds__(256) void zero_counters(int* __restrict__ counters)
{
    counters[threadIdx.x] = 0;
}

// ---------- kernel B: one thread per (n,m) pair; emit events into buckets ----------
// w[k][m] > 0 requires ||nb - kp|| < 0.05 with ||kp|| <= 0.0495
//   => ||nb||^2 < 0.009901  (use 0.0101 conservative)
template <int USE_S4>
__global__ __launch_bounds__(256) void pair_kernel(
    const float*  __restrict__ query,     // [N,3]
    const float*  __restrict__ support,   // [N0,3] (fallback)
    const float4* __restrict__ s4,        // [N0]   (fast path)
    const int*    __restrict__ neighbors, // [N,M] flat
    const float*  __restrict__ kpts,      // [K,3]
    int*          __restrict__ counters,  // [NBUCK]
    int4*         __restrict__ events,    // [NBUCK][cap]
    int cap)
{
    __shared__ float s_kx[K_PTS], s_ky[K_PTS], s_kz[K_PTS], s_kk[K_PTS];
    if (threadIdx.x < K_PTS) {
        float kx = kpts[threadIdx.x * 3 + 0];
        float ky = kpts[threadIdx.x * 3 + 1];
        float kz = kpts[threadIdx.x * 3 + 2];
        s_kx[threadIdx.x] = kx; s_ky[threadIdx.x] = ky; s_kz[threadIdx.x] = kz;
        s_kk[threadIdx.x] = kx * kx + ky * ky + kz * kz;
    }
    __syncthreads();

    const int t = blockIdx.x * 256 + threadIdx.x;   // grid == NPAIRS threads
    const int n = t >> 5;
    const int idx = neighbors[t];                   // coalesced
    if (idx >= N_S) return;                         // shadow neighbor: w == 0

    float sx, sy, sz;
    if (USE_S4) {
        float4 s = s4[idx];                         // one dwordx4 gather
        sx = s.x; sy = s.y; sz = s.z;
    } else {
        sx = support[idx * 3 + 0];
        sy = support[idx * 3 + 1];
        sz = support[idx * 3 + 2];
    }
    const float dx = sx - query[n * 3 + 0];
    const float dy = sy - query[n * 3 + 1];
    const float dz = sz - query[n * 3 + 2];
    const float nn = dx * dx + dy * dy + dz * dz;
    if (nn >= 0.0101f) return;

    const int bucket = blockIdx.x & (NBUCK - 1);
    int* ctr  = counters + bucket;
    int4* evb = events + (size_t)bucket * cap;

    #pragma unroll
    for (int k = 0; k < K_PTS; ++k) {
        float dot = dx * s_kx[k] + dy * s_ky[k] + dz * s_kz[k];
        float sq  = nn - 2.f * dot + s_kk[k];       // same expansion as reference
        sq = fmaxf(sq, 0.f);
        if (sq < 0.0025f) {                          // sqrt(sq) < 0.05 => w > 0
            float w = 1.f - sqrtf(sq) * 20.f;        // 1/0.05 == 20 exactly
            int slot = atomicAdd(ctr, 1);
            if (slot < cap)
                evb[slot] = make_int4(n, k, idx, __float_as_int(w));
        }
    }
}

// ---------- kernel C: 8 blocks per bucket; scalar x-loads; 4 accumulators ----------
__global__ __launch_bounds__(256) void gemv_kernel(
    const int*  __restrict__ counters,
    const int4* __restrict__ events,
    int cap,
    const float* __restrict__ x,       // [N0,CIN]
    const float* __restrict__ weight,  // [K,CIN,COUT]
    float*       __restrict__ out)     // [N,COUT]
{
    const int lane = threadIdx.x & 63;
    const int wv   = threadIdx.x >> 6;                       // 0..3
    const int b    = blockIdx.x >> 3;                        // bucket
    const int sub  = blockIdx.x & (GEMV_BLOCKS_PER_BUCKET-1);
    const int cnt  = min(counters[b], cap);
    const int4* evb = events + (size_t)b * cap;

    for (int e = sub * 4 + wv; e < cnt; e += 4 * GEMV_BLOCKS_PER_BUCKET) {
        const int4 ev = evb[e];
        // ev is wave-uniform: hoist to SGPRs so x-row reads become s_loads
        const int   n   = __builtin_amdgcn_readfirstlane(ev.x);
        const int   k   = __builtin_amdgcn_readfirstlane(ev.y);
        const int   idx = __builtin_amdgcn_readfirstlane(ev.z);
        const float w   = __int_as_float(__builtin_amdgcn_readfirstlane(ev.w));

        const float* xr = x + (size_t)idx * CIN;             // uniform -> s_load
        const float* wp = weight + (size_t)k * CIN * COUT + lane;

        float t0 = 0.f, t1 = 0.f, t2 = 0.f, t3 = 0.f;
        #pragma unroll
        for (int c = 0; c < CIN; c += 4) {
            t0 = fmaf(xr[c + 0], wp[(c + 0) * COUT], t0);
            t1 = fmaf(xr[c + 1], wp[(c + 1) * COUT], t1);
            t2 = fmaf(xr[c + 2], wp[(c + 2) * COUT], t2);
            t3 = fmaf(xr[c + 3], wp[(c + 3) * COUT], t3);
        }
        atomicAdd(&out[(size_t)n * COUT + lane], w * ((t0 + t1) + (t2 + t3)));
    }
}

extern "C" void kernel_launch(void* const* d_in, const int* in_sizes, int n_in,
                              void* d_out, int out_size, void* d_ws, size_t ws_size,
                              hipStream_t stream) {
    const float* query     = (const float*)d_in[0];
    const float* support   = (const float*)d_in[1];
    const int*   neighbors = (const int*)  d_in[2];
    const float* x         = (const float*)d_in[3];
    const float* kpts      = (const float*)d_in[4];
    const float* weight    = (const float*)d_in[5];
    float*       out       = (float*)d_out;

    char*   ws       = (char*)d_ws;
    int*    counters = (int*)ws;
    float4* s4       = (float4*)(ws + CTR_BYTES);

    const bool use_s4 = ws_size >= (size_t)EV_OFF + (2u << 20);
    int4* events;
    int   cap;
    if (use_s4) {
        events = (int4*)(ws + EV_OFF);
        cap    = (int)((ws_size - EV_OFF) / sizeof(int4) / NBUCK);
    } else {
        events = (int4*)(ws + CTR_BYTES);
        cap    = (int)((ws_size - CTR_BYTES) / sizeof(int4) / NBUCK);
    }

    hipMemsetAsync(d_out, 0, (size_t)N_Q * COUT * sizeof(float), stream);

    if (use_s4) {
        transpose_support<<<(N_S + 255) / 256, 256, 0, stream>>>(support, s4, counters);
        pair_kernel<1><<<NPAIRS / 256, 256, 0, stream>>>(
            query, support, s4, neighbors, kpts, counters, events, cap);
    } else {
        zero_counters<<<1, 256, 0, stream>>>(counters);
        pair_kernel<0><<<NPAIRS / 256, 256, 0, stream>>>(
            query, support, s4, neighbors, kpts, counters, events, cap);
    }
    gemv_kernel<<<NBUCK * GEMV_BLOCKS_PER_BUCKET, 256, 0, stream>>>(
        counters, events, cap, x, weight, out);
}

// Round 5
// 44.242 us; speedup vs baseline: 4.5984x; 1.0586x over previous
//
#include <hip/hip_runtime.h>

#define N_Q   50000
#define N_S   50000
#define M_NB  32
#define K_PTS 15
#define CIN   64
#define COUT  64
#define NPAIRS (N_Q * M_NB)
#define NBUCK 256
#define GEMV_BLOCKS_PER_BUCKET 8

// ws layout:
//   [0, 1024)             : int counters[NBUCK]
//   [1024, 1024 + N_S*16) : float4 s4[N_S]
//   [EV_OFF, ...)         : int4 events[NBUCK][cap]
#define CTR_BYTES 1024
#define S4_BYTES  (N_S * 16)
#define EV_OFF    (CTR_BYTES + S4_BYTES)

// ---------- kernel A: zero out + zero counters + support [N0,3]->float4 ----------
template <int DO_S4>
__global__ __launch_bounds__(256) void prep_kernel(
    const float* __restrict__ support,
    float4*      __restrict__ s4,
    int*         __restrict__ counters,
    float4*      __restrict__ out4)     // N_Q*COUT/4 float4s
{
    const int t  = blockIdx.x * 256 + threadIdx.x;
    const int nt = gridDim.x * 256;

    if (t < NBUCK) counters[t] = 0;

    if (DO_S4) {
        for (int i = t; i < N_S; i += nt)
            s4[i] = make_float4(support[i * 3 + 0], support[i * 3 + 1],
                                support[i * 3 + 2], 0.f);
    }

    const int nout4 = N_Q * COUT / 4;
    const float4 z = make_float4(0.f, 0.f, 0.f, 0.f);
    for (int i = t; i < nout4; i += nt)
        out4[i] = z;
}

// ---------- kernel B: one thread per (n,m) pair; emit events into buckets ----------
// w[k][m] > 0 requires ||nb - kp|| < 0.05 with ||kp|| <= 0.0495
//   => ||nb||^2 < 0.009901  (use 0.0101 conservative)
template <int USE_S4>
__global__ __launch_bounds__(256) void pair_kernel(
    const float*  __restrict__ query,     // [N,3]
    const float*  __restrict__ support,   // [N0,3] (fallback)
    const float4* __restrict__ s4,        // [N0]   (fast path)
    const int*    __restrict__ neighbors, // [N,M] flat
    const float*  __restrict__ kpts,      // [K,3]
    int*          __restrict__ counters,  // [NBUCK]
    int4*         __restrict__ events,    // [NBUCK][cap]
    int cap)
{
    __shared__ float s_kx[K_PTS], s_ky[K_PTS], s_kz[K_PTS], s_kk[K_PTS];
    if (threadIdx.x < K_PTS) {
        float kx = kpts[threadIdx.x * 3 + 0];
        float ky = kpts[threadIdx.x * 3 + 1];
        float kz = kpts[threadIdx.x * 3 + 2];
        s_kx[threadIdx.x] = kx; s_ky[threadIdx.x] = ky; s_kz[threadIdx.x] = kz;
        s_kk[threadIdx.x] = kx * kx + ky * ky + kz * kz;
    }
    __syncthreads();

    const int t = blockIdx.x * 256 + threadIdx.x;   // grid == NPAIRS threads
    const int n = t >> 5;
    const int idx = neighbors[t];                   // coalesced
    if (idx >= N_S) return;                         // shadow neighbor: w == 0

    float sx, sy, sz;
    if (USE_S4) {
        float4 s = s4[idx];                         // one dwordx4 gather
        sx = s.x; sy = s.y; sz = s.z;
    } else {
        sx = support[idx * 3 + 0];
        sy = support[idx * 3 + 1];
        sz = support[idx * 3 + 2];
    }
    const float dx = sx - query[n * 3 + 0];
    const float dy = sy - query[n * 3 + 1];
    const float dz = sz - query[n * 3 + 2];
    const float nn = dx * dx + dy * dy + dz * dz;
    if (nn >= 0.0101f) return;

    const int bucket = blockIdx.x & (NBUCK - 1);
    int* ctr  = counters + bucket;
    int4* evb = events + (size_t)bucket * cap;

    #pragma unroll
    for (int k = 0; k < K_PTS; ++k) {
        float dot = dx * s_kx[k] + dy * s_ky[k] + dz * s_kz[k];
        float sq  = nn - 2.f * dot + s_kk[k];       // same expansion as reference
        sq = fmaxf(sq, 0.f);
        if (sq < 0.0025f) {                          // sqrt(sq) < 0.05 => w > 0
            float w = 1.f - sqrtf(sq) * 20.f;        // 1/0.05 == 20 exactly
            int slot = atomicAdd(ctr, 1);
            if (slot < cap)
                evb[slot] = make_int4(n, k, idx, __float_as_int(w));
        }
    }
}

// ---------- kernel C: 8 blocks per bucket; scalar x-loads; 4 accumulators ----------
__global__ __launch_bounds__(256) void gemv_kernel(
    const int*  __restrict__ counters,
    const int4* __restrict__ events,
    int cap,
    const float* __restrict__ x,       // [N0,CIN]
    const float* __restrict__ weight,  // [K,CIN,COUT]
    float*       __restrict__ out)     // [N,COUT]
{
    const int lane = threadIdx.x & 63;
    const int wv   = threadIdx.x >> 6;                       // 0..3
    const int b    = blockIdx.x >> 3;                        // bucket
    const int sub  = blockIdx.x & (GEMV_BLOCKS_PER_BUCKET-1);
    const int cnt  = min(counters[b], cap);
    const int4* evb = events + (size_t)b * cap;

    for (int e = sub * 4 + wv; e < cnt; e += 4 * GEMV_BLOCKS_PER_BUCKET) {
        const int4 ev = evb[e];
        // ev is wave-uniform: hoist to SGPRs so x-row reads become s_loads
        const int   n   = __builtin_amdgcn_readfirstlane(ev.x);
        const int   k   = __builtin_amdgcn_readfirstlane(ev.y);
        const int   idx = __builtin_amdgcn_readfirstlane(ev.z);
        const float w   = __int_as_float(__builtin_amdgcn_readfirstlane(ev.w));

        const float* xr = x + (size_t)idx * CIN;             // uniform -> s_load
        const float* wp = weight + (size_t)k * CIN * COUT + lane;

        float t0 = 0.f, t1 = 0.f, t2 = 0.f, t3 = 0.f;
        #pragma unroll
        for (int c = 0; c < CIN; c += 4) {
            t0 = fmaf(xr[c + 0], wp[(c + 0) * COUT], t0);
            t1 = fmaf(xr[c + 1], wp[(c + 1) * COUT], t1);
            t2 = fmaf(xr[c + 2], wp[(c + 2) * COUT], t2);
            t3 = fmaf(xr[c + 3], wp[(c + 3) * COUT], t3);
        }
        atomicAdd(&out[(size_t)n * COUT + lane], w * ((t0 + t1) + (t2 + t3)));
    }
}

extern "C" void kernel_launch(void* const* d_in, const int* in_sizes, int n_in,
                              void* d_out, int out_size, void* d_ws, size_t ws_size,
                              hipStream_t stream) {
    const float* query     = (const float*)d_in[0];
    const float* support   = (const float*)d_in[1];
    const int*   neighbors = (const int*)  d_in[2];
    const float* x         = (const float*)d_in[3];
    const float* kpts      = (const float*)d_in[4];
    const float* weight    = (const float*)d_in[5];
    float*       out       = (float*)d_out;

    char*   ws       = (char*)d_ws;
    int*    counters = (int*)ws;
    float4* s4       = (float4*)(ws + CTR_BYTES);

    const bool use_s4 = ws_size >= (size_t)EV_OFF + (2u << 20);
    int4* events;
    int   cap;
    if (use_s4) {
        events = (int4*)(ws + EV_OFF);
        cap    = (int)((ws_size - EV_OFF) / sizeof(int4) / NBUCK);
    } else {
        events = (int4*)(ws + CTR_BYTES);
        cap    = (int)((ws_size - CTR_BYTES) / sizeof(int4) / NBUCK);
    }

    if (use_s4) {
        prep_kernel<1><<<2048, 256, 0, stream>>>(support, s4, counters, (float4*)out);
        pair_kernel<1><<<NPAIRS / 256, 256, 0, stream>>>(
            query, support, s4, neighbors, kpts, counters, events, cap);
    } else {
        prep_kernel<0><<<2048, 256, 0, stream>>>(support, s4, counters, (float4*)out);
        pair_kernel<0><<<NPAIRS / 256, 256, 0, stream>>>(
            query, support, s4, neighbors, kpts, counters, events, cap);
    }
    gemv_kernel<<<NBUCK * GEMV_BLOCKS_PER_BUCKET, 256, 0, stream>>>(
        counters, events, cap, x, weight, out);
}